// Round 1
// baseline (1009.400 us; speedup 1.0000x reference)
//
#include <hip/hip_runtime.h>

#define B_DIM 1024
#define NT 128
#define NY 128
#define C_DIM 512
#define EOS 1

// One wave (64 lanes) per batch element. Lane owns j0=2*lane, j1=2*lane+1.
// Per t-step: gather pred/I columns (prefetched), build affine elements
// (a_j, d_j) for new_row[j] = a_j + d_j * new_row[j-1], compose the lane's
// two elements, wave-wide inclusive affine scan via __shfl_up (6 steps).
__global__ __launch_bounds__(64) void eploss_kernel(
    const float* __restrict__ pred,
    const float* __restrict__ R,
    const float* __restrict__ I,
    const int*   __restrict__ target,
    float*       __restrict__ out)
{
    const int b    = blockIdx.x;
    const int lane = threadIdx.x;     // 0..63
    const int j0   = 2 * lane;
    const int j1   = 2 * lane + 1;

    __shared__ int tg[NT];
    tg[j0] = target[(size_t)b * NT + j0];
    tg[j1] = target[(size_t)b * NT + j1];
    __syncthreads();

    // Preload R rows for this lane's two j's (contiguous 6 floats per lane).
    const float* Rb = R + (size_t)b * NY * 3;
    const float R0j0 = Rb[j0 * 3 + 0];
    const float R1j0 = Rb[j0 * 3 + 1];
    const float R2j0 = Rb[j0 * 3 + 2];
    const float R0j1 = Rb[j1 * 3 + 0];
    const float R1j1 = Rb[j1 * 3 + 1];
    const float R2j1 = Rb[j1 * 3 + 2];
    const float R2m1 = __shfl_up(R2j1, 1);   // R2[j0-1] (lane>0)

    // ---- row0: cumprod of [1, pD0[1..127]] ----
    const int tgt0 = tg[0];
    const float e0 = (lane == 0) ? 1.0f : ((tgt0 == EOS) ? 1.0f : R2j0);
    const float e1 = (tgt0 == EOS) ? 1.0f : R2j1;
    float P = e0 * e1;
    #pragma unroll
    for (int s = 1; s < 64; s <<= 1) {
        float Pp = __shfl_up(P, s);
        if (lane >= s) P *= Pp;
    }
    float Pm1 = __shfl_up(P, 1);
    if (lane == 0) Pm1 = 1.0f;
    float row0v = Pm1 * e0;   // row[j0]
    float row1v = P;          // row[j1]

    // Gather base pointers for this lane's two rows.
    const size_t baseP = (size_t)b * NY * C_DIM;
    const float* pr0 = pred + baseP + (size_t)j0 * C_DIM;
    const float* pr1 = pred + baseP + (size_t)j1 * C_DIM;
    const float* Ii0 = I    + baseP + (size_t)j0 * C_DIM;
    const float* Ii1 = I    + baseP + (size_t)j1 * C_DIM;

    int tgt = tg[0];
    float p0 = pr0[tgt], p1 = pr1[tgt];
    float q0 = Ii0[tgt], q1 = Ii1[tgt];

    for (int t = 0; t < NT - 1; ++t) {
        const int tgt_next = tg[t + 1];

        // Prefetch next step's gathers while we do this step's scan.
        float np0 = 0.f, np1 = 0.f, nq0 = 0.f, nq1 = 0.f;
        if (t + 1 < NT - 1) {
            np0 = pr0[tgt_next]; np1 = pr1[tgt_next];
            nq0 = Ii0[tgt_next]; nq1 = Ii1[tgt_next];
        }

        const float pC0 = R0j0 * p0;
        const float pC1 = R0j1 * p1;
        const float pI0 = R1j0 * q0;
        const float pI1 = (lane == 63) ? q1 : R1j1 * q1;   // p_I[...,127] = I_T

        const float m0 = row0v * pC0;
        const float m1 = row1v * pC1;
        const float mprev = __shfl_up(m1, 1);              // m[j0-1]

        const float a0 = row0v * pI0 + ((lane == 0) ? 0.0f : mprev);
        const float a1 = m0 + row1v * pI1;

        const bool eosn = (tgt_next == EOS);
        const float d0 = (lane == 0 || eosn) ? 1.0f : R2m1; // d_full[j0] = pD_next[j0-1]
        const float d1 = eosn ? 1.0f : R2j0;                // d_full[j1] = pD_next[j0]

        // Lane-local compose: x_{j1} = (a1 + d1*a0) + (d1*d0) * x_{j0-1}
        float A = a1 + d1 * a0;
        float D = d1 * d0;

        // Wave-wide inclusive affine scan: op(l, r) = (a_r + a_l*d_r, d_l*d_r)
        #pragma unroll
        for (int s = 1; s < 64; s <<= 1) {
            float Ap = __shfl_up(A, s);
            float Dp = __shfl_up(D, s);
            if (lane >= s) { A = A + Ap * D; D = D * Dp; }
        }

        const float Xm1 = __shfl_up(A, 1);                 // x_{j0-1}
        row0v = a0 + ((lane == 0) ? 0.0f : d0 * Xm1);
        row1v = A;

        p0 = np0; p1 = np1; q0 = nq0; q1 = nq1;
    }

    if (lane == 63) out[b] = row1v;   // row_final[:, -1]
}

extern "C" void kernel_launch(void* const* d_in, const int* in_sizes, int n_in,
                              void* d_out, int out_size, void* d_ws, size_t ws_size,
                              hipStream_t stream) {
    const float* pred   = (const float*)d_in[0];
    const float* R      = (const float*)d_in[1];
    const float* I      = (const float*)d_in[2];
    const int*   target = (const int*)d_in[3];
    float* out = (float*)d_out;

    eploss_kernel<<<dim3(B_DIM), dim3(64), 0, stream>>>(pred, R, I, target, out);
}

// Round 2
// 589.010 us; speedup vs baseline: 1.7137x; 1.7137x over previous
//
#include <hip/hip_runtime.h>

#define B_DIM 1024
#define NT 128
#define NY 128
#define C_DIM 512
#define EOS 1

// ---------------- Kernel 1: row-streaming gather ----------------
// G[b][j][t] = src[b][j][target[b][t]]  for src in {pred, I}.
// Grid (B, 2): block handles 64 rows x 2 arrays = 128 tasks, 4 waves x 32.
// Each task: stream one 2KB row coalesced -> LDS, extract 128 targets,
// write G row coalesced. Every HBM line of pred/I is read exactly once.
__global__ __launch_bounds__(256) void gather_kernel(
    const float* __restrict__ pred,
    const float* __restrict__ I,
    const int*   __restrict__ target,
    float*       __restrict__ Gp,   // [B][NY][NT]
    float*       __restrict__ Gi)   // [B][NY][NT]
{
    const int b    = blockIdx.x;
    const int half = blockIdx.y;            // rows [half*64, half*64+64)
    const int wave = threadIdx.x >> 6;      // 0..3
    const int lane = threadIdx.x & 63;

    __shared__ float rowbuf[4][C_DIM];      // 2KB per wave

    // Per-lane targets in registers: lane covers t=lane and t=lane+64.
    const int tgA = target[b * NT + lane];
    const int tgB = target[b * NT + 64 + lane];

    const size_t abase = (size_t)b * NY * C_DIM;
    const size_t gbase = (size_t)b * NY * NT;

    auto srcptr = [&](int tk) -> const float* {
        const int j = half * 64 + (tk & 63);
        return (tk < 64 ? pred : I) + abase + (size_t)j * C_DIM;
    };

    int task = wave * 32;
    float4 v0 = *(const float4*)(srcptr(task) + lane * 8);
    float4 v1 = *(const float4*)(srcptr(task) + lane * 8 + 4);

    for (int it = 0; it < 32; ++it) {
        task = wave * 32 + it;
        // Stage current row to this wave's LDS buffer.
        *(float4*)&rowbuf[wave][lane * 8]     = v0;
        *(float4*)&rowbuf[wave][lane * 8 + 4] = v1;
        // Prefetch next row while extracting this one.
        if (it < 31) {
            const float* ns = srcptr(task + 1);
            v0 = *(const float4*)(ns + lane * 8);
            v1 = *(const float4*)(ns + lane * 8 + 4);
        }
        // Wave-synchronous LDS: ensure our wave's ds_writes completed.
        asm volatile("s_waitcnt lgkmcnt(0)" ::: "memory");
        const float gA = rowbuf[wave][tgA];
        const float gB = rowbuf[wave][tgB];
        const int j = half * 64 + (task & 63);
        float* dst = (task < 64 ? Gp : Gi) + gbase + (size_t)j * NT;
        dst[lane]      = gA;
        dst[lane + 64] = gB;
    }
}

// ---------------- Kernel 2: per-batch affine scan ----------------
// One wave per b; lane owns j0=2*lane, j1=2*lane+1. Same math as before,
// but reads pre-gathered G[b][j][t] as float4 chunks (4 t per load).
__global__ __launch_bounds__(64) void scan_kernel(
    const float* __restrict__ R,
    const int*   __restrict__ target,
    const float* __restrict__ Gp,
    const float* __restrict__ Gi,
    float*       __restrict__ out)
{
    const int b    = blockIdx.x;
    const int lane = threadIdx.x;
    const int j0   = 2 * lane;
    const int j1   = 2 * lane + 1;

    __shared__ int tg[NT];
    tg[j0] = target[(size_t)b * NT + j0];
    tg[j1] = target[(size_t)b * NT + j1];
    __syncthreads();

    const float* Rb = R + (size_t)b * NY * 3;
    const float R0j0 = Rb[j0 * 3 + 0];
    const float R1j0 = Rb[j0 * 3 + 1];
    const float R2j0 = Rb[j0 * 3 + 2];
    const float R0j1 = Rb[j1 * 3 + 0];
    const float R1j1 = Rb[j1 * 3 + 1];
    const float R2j1 = Rb[j1 * 3 + 2];
    const float R2m1 = __shfl_up(R2j1, 1);   // R2[j0-1] (lane>0)

    // row0 = cumprod([1, pD0[1..127]])
    const int tgt0 = tg[0];
    const float e0 = (lane == 0) ? 1.0f : ((tgt0 == EOS) ? 1.0f : R2j0);
    const float e1 = (tgt0 == EOS) ? 1.0f : R2j1;
    float P = e0 * e1;
    #pragma unroll
    for (int s = 1; s < 64; s <<= 1) {
        float Pp = __shfl_up(P, s);
        if (lane >= s) P *= Pp;
    }
    float Pm1 = __shfl_up(P, 1);
    if (lane == 0) Pm1 = 1.0f;
    float row0v = Pm1 * e0;
    float row1v = P;

    const size_t gbase = (size_t)b * NY * NT;
    const float* gp0 = Gp + gbase + (size_t)j0 * NT;
    const float* gp1 = Gp + gbase + (size_t)j1 * NT;
    const float* gi0 = Gi + gbase + (size_t)j0 * NT;
    const float* gi1 = Gi + gbase + (size_t)j1 * NT;

    auto step = [&](float p0, float p1, float q0, float q1, int tgt_next) {
        const float pC0 = R0j0 * p0;
        const float pC1 = R0j1 * p1;
        const float pI0 = R1j0 * q0;
        const float pI1 = (lane == 63) ? q1 : R1j1 * q1;   // p_I[...,127] = I_T
        const float m1 = row1v * pC1;
        const float mprev = __shfl_up(m1, 1);
        const float a0 = row0v * pI0 + ((lane == 0) ? 0.0f : mprev);
        const float a1 = row0v * pC0 + row1v * pI1;
        const bool eosn = (tgt_next == EOS);
        const float d0 = (lane == 0 || eosn) ? 1.0f : R2m1;
        const float d1 = eosn ? 1.0f : R2j0;
        float A = a1 + d1 * a0;
        float D = d1 * d0;
        #pragma unroll
        for (int s = 1; s < 64; s <<= 1) {
            float Ap = __shfl_up(A, s);
            float Dp = __shfl_up(D, s);
            if (lane >= s) { A = A + Ap * D; D = D * Dp; }
        }
        const float Xm1 = __shfl_up(A, 1);
        row0v = a0 + ((lane == 0) ? 0.0f : d0 * Xm1);
        row1v = A;
    };

    float4 cP0 = *(const float4*)(gp0);
    float4 cP1 = *(const float4*)(gp1);
    float4 cQ0 = *(const float4*)(gi0);
    float4 cQ1 = *(const float4*)(gi1);

    for (int tb = 0; tb < 124; tb += 4) {
        const float4 nP0 = *(const float4*)(gp0 + tb + 4);
        const float4 nP1 = *(const float4*)(gp1 + tb + 4);
        const float4 nQ0 = *(const float4*)(gi0 + tb + 4);
        const float4 nQ1 = *(const float4*)(gi1 + tb + 4);
        step(cP0.x, cP1.x, cQ0.x, cQ1.x, tg[tb + 1]);
        step(cP0.y, cP1.y, cQ0.y, cQ1.y, tg[tb + 2]);
        step(cP0.z, cP1.z, cQ0.z, cQ1.z, tg[tb + 3]);
        step(cP0.w, cP1.w, cQ0.w, cQ1.w, tg[tb + 4]);
        cP0 = nP0; cP1 = nP1; cQ0 = nQ0; cQ1 = nQ1;
    }
    // t = 124, 125, 126
    step(cP0.x, cP1.x, cQ0.x, cQ1.x, tg[125]);
    step(cP0.y, cP1.y, cQ0.y, cQ1.y, tg[126]);
    step(cP0.z, cP1.z, cQ0.z, cQ1.z, tg[127]);

    if (lane == 63) out[b] = row1v;
}

// ---------------- Fallback (round-1 kernel) if ws too small ----------------
__global__ __launch_bounds__(64) void eploss_fallback(
    const float* __restrict__ pred,
    const float* __restrict__ R,
    const float* __restrict__ I,
    const int*   __restrict__ target,
    float*       __restrict__ out)
{
    const int b    = blockIdx.x;
    const int lane = threadIdx.x;
    const int j0   = 2 * lane;
    const int j1   = 2 * lane + 1;

    __shared__ int tg[NT];
    tg[j0] = target[(size_t)b * NT + j0];
    tg[j1] = target[(size_t)b * NT + j1];
    __syncthreads();

    const float* Rb = R + (size_t)b * NY * 3;
    const float R0j0 = Rb[j0 * 3 + 0];
    const float R1j0 = Rb[j0 * 3 + 1];
    const float R2j0 = Rb[j0 * 3 + 2];
    const float R0j1 = Rb[j1 * 3 + 0];
    const float R1j1 = Rb[j1 * 3 + 1];
    const float R2j1 = Rb[j1 * 3 + 2];
    const float R2m1 = __shfl_up(R2j1, 1);

    const int tgt0 = tg[0];
    const float e0 = (lane == 0) ? 1.0f : ((tgt0 == EOS) ? 1.0f : R2j0);
    const float e1 = (tgt0 == EOS) ? 1.0f : R2j1;
    float P = e0 * e1;
    #pragma unroll
    for (int s = 1; s < 64; s <<= 1) {
        float Pp = __shfl_up(P, s);
        if (lane >= s) P *= Pp;
    }
    float Pm1 = __shfl_up(P, 1);
    if (lane == 0) Pm1 = 1.0f;
    float row0v = Pm1 * e0;
    float row1v = P;

    const size_t baseP = (size_t)b * NY * C_DIM;
    const float* pr0 = pred + baseP + (size_t)j0 * C_DIM;
    const float* pr1 = pred + baseP + (size_t)j1 * C_DIM;
    const float* Ii0 = I    + baseP + (size_t)j0 * C_DIM;
    const float* Ii1 = I    + baseP + (size_t)j1 * C_DIM;

    int tgt = tg[0];
    float p0 = pr0[tgt], p1 = pr1[tgt];
    float q0 = Ii0[tgt], q1 = Ii1[tgt];

    for (int t = 0; t < NT - 1; ++t) {
        const int tgt_next = tg[t + 1];
        float np0 = 0.f, np1 = 0.f, nq0 = 0.f, nq1 = 0.f;
        if (t + 1 < NT - 1) {
            np0 = pr0[tgt_next]; np1 = pr1[tgt_next];
            nq0 = Ii0[tgt_next]; nq1 = Ii1[tgt_next];
        }
        const float pC0 = R0j0 * p0;
        const float pC1 = R0j1 * p1;
        const float pI0 = R1j0 * q0;
        const float pI1 = (lane == 63) ? q1 : R1j1 * q1;
        const float m1 = row1v * pC1;
        const float mprev = __shfl_up(m1, 1);
        const float a0 = row0v * pI0 + ((lane == 0) ? 0.0f : mprev);
        const float a1 = row0v * pC0 + row1v * pI1;
        const bool eosn = (tgt_next == EOS);
        const float d0 = (lane == 0 || eosn) ? 1.0f : R2m1;
        const float d1 = eosn ? 1.0f : R2j0;
        float A = a1 + d1 * a0;
        float D = d1 * d0;
        #pragma unroll
        for (int s = 1; s < 64; s <<= 1) {
            float Ap = __shfl_up(A, s);
            float Dp = __shfl_up(D, s);
            if (lane >= s) { A = A + Ap * D; D = D * Dp; }
        }
        const float Xm1 = __shfl_up(A, 1);
        row0v = a0 + ((lane == 0) ? 0.0f : d0 * Xm1);
        row1v = A;
        p0 = np0; p1 = np1; q0 = nq0; q1 = nq1;
    }

    if (lane == 63) out[b] = row1v;
}

extern "C" void kernel_launch(void* const* d_in, const int* in_sizes, int n_in,
                              void* d_out, int out_size, void* d_ws, size_t ws_size,
                              hipStream_t stream) {
    const float* pred   = (const float*)d_in[0];
    const float* R      = (const float*)d_in[1];
    const float* I      = (const float*)d_in[2];
    const int*   target = (const int*)d_in[3];
    float* out = (float*)d_out;

    const size_t need = 2ull * B_DIM * NY * NT * sizeof(float);  // 134 MB
    if (ws_size >= need) {
        float* Gp = (float*)d_ws;
        float* Gi = Gp + (size_t)B_DIM * NY * NT;
        gather_kernel<<<dim3(B_DIM, 2), dim3(256), 0, stream>>>(pred, I, target, Gp, Gi);
        scan_kernel<<<dim3(B_DIM), dim3(64), 0, stream>>>(R, target, Gp, Gi, out);
    } else {
        eploss_fallback<<<dim3(B_DIM), dim3(64), 0, stream>>>(pred, R, I, target, out);
    }
}

// Round 3
// 575.132 us; speedup vs baseline: 1.7551x; 1.0241x over previous
//
#include <hip/hip_runtime.h>

#define B_DIM 1024
#define NT 128
#define NY 128
#define C_DIM 512
#define EOS 1

// ---------------- Kernel 1: direct L1-merged gather ----------------
// One wave per (b, j). Lane l gathers row[target[b,l]] and row[target[b,64+l]]
// for both pred and I. All 64 random addresses fall inside one 2KB row
// (32 cache lines) -> L1/MSHR merges them into <=32 line fills; each line is
// fetched from L2 exactly once. No LDS, tiny VGPR count -> 8 waves/SIMD MLP.
// G layout [b][j][t]: stores are 256B-coalesced per instruction.
__global__ __launch_bounds__(256) void gather_direct(
    const float* __restrict__ pred,
    const float* __restrict__ I,
    const int*   __restrict__ target,
    float*       __restrict__ Gp,   // [B][NY][NT]
    float*       __restrict__ Gi)   // [B][NY][NT]
{
    const int wid  = blockIdx.x * 4 + (threadIdx.x >> 6); // = b*NY + j
    const int lane = threadIdx.x & 63;
    const int b = wid >> 7;
    const int j = wid & (NY - 1);

    const int tA = target[b * NT + lane];
    const int tB = target[b * NT + 64 + lane];

    const size_t rbase = ((size_t)b * NY + j) * C_DIM;
    const float* pr = pred + rbase;
    const float* ii = I    + rbase;

    const float pA = pr[tA];
    const float pB = pr[tB];
    const float iA = ii[tA];
    const float iB = ii[tB];

    const size_t gbase = ((size_t)b * NY + j) * NT;
    float* gp = Gp + gbase;
    float* gi = Gi + gbase;
    gp[lane]      = pA;
    gp[64 + lane] = pB;
    gi[lane]      = iA;
    gi[64 + lane] = iB;
}

// ---------------- Kernel 2: per-batch affine scan ----------------
// One wave per b; lane owns j0=2*lane, j1=2*lane+1. Reads pre-gathered
// G[b][j][t] as float4 chunks (4 t per load, full 64B line over 4 iters).
__global__ __launch_bounds__(64) void scan_kernel(
    const float* __restrict__ R,
    const int*   __restrict__ target,
    const float* __restrict__ Gp,
    const float* __restrict__ Gi,
    float*       __restrict__ out)
{
    const int b    = blockIdx.x;
    const int lane = threadIdx.x;
    const int j0   = 2 * lane;
    const int j1   = 2 * lane + 1;

    __shared__ int tg[NT];
    tg[j0] = target[(size_t)b * NT + j0];
    tg[j1] = target[(size_t)b * NT + j1];
    __syncthreads();

    const float* Rb = R + (size_t)b * NY * 3;
    const float R0j0 = Rb[j0 * 3 + 0];
    const float R1j0 = Rb[j0 * 3 + 1];
    const float R2j0 = Rb[j0 * 3 + 2];
    const float R0j1 = Rb[j1 * 3 + 0];
    const float R1j1 = Rb[j1 * 3 + 1];
    const float R2j1 = Rb[j1 * 3 + 2];
    const float R2m1 = __shfl_up(R2j1, 1);   // R2[j0-1] (lane>0)

    // row0 = cumprod([1, pD0[1..127]])
    const int tgt0 = tg[0];
    const float e0 = (lane == 0) ? 1.0f : ((tgt0 == EOS) ? 1.0f : R2j0);
    const float e1 = (tgt0 == EOS) ? 1.0f : R2j1;
    float P = e0 * e1;
    #pragma unroll
    for (int s = 1; s < 64; s <<= 1) {
        float Pp = __shfl_up(P, s);
        if (lane >= s) P *= Pp;
    }
    float Pm1 = __shfl_up(P, 1);
    if (lane == 0) Pm1 = 1.0f;
    float row0v = Pm1 * e0;
    float row1v = P;

    const size_t gbase = (size_t)b * NY * NT;
    const float* gp0 = Gp + gbase + (size_t)j0 * NT;
    const float* gp1 = Gp + gbase + (size_t)j1 * NT;
    const float* gi0 = Gi + gbase + (size_t)j0 * NT;
    const float* gi1 = Gi + gbase + (size_t)j1 * NT;

    auto step = [&](float p0, float p1, float q0, float q1, int tgt_next) {
        const float pC0 = R0j0 * p0;
        const float pC1 = R0j1 * p1;
        const float pI0 = R1j0 * q0;
        const float pI1 = (lane == 63) ? q1 : R1j1 * q1;   // p_I[...,127] = I_T
        const float m1 = row1v * pC1;
        const float mprev = __shfl_up(m1, 1);
        const float a0 = row0v * pI0 + ((lane == 0) ? 0.0f : mprev);
        const float a1 = row0v * pC0 + row1v * pI1;
        const bool eosn = (tgt_next == EOS);
        const float d0 = (lane == 0 || eosn) ? 1.0f : R2m1;
        const float d1 = eosn ? 1.0f : R2j0;
        float A = a1 + d1 * a0;
        float D = d1 * d0;
        #pragma unroll
        for (int s = 1; s < 64; s <<= 1) {
            float Ap = __shfl_up(A, s);
            float Dp = __shfl_up(D, s);
            if (lane >= s) { A = A + Ap * D; D = D * Dp; }
        }
        const float Xm1 = __shfl_up(A, 1);
        row0v = a0 + ((lane == 0) ? 0.0f : d0 * Xm1);
        row1v = A;
    };

    float4 cP0 = *(const float4*)(gp0);
    float4 cP1 = *(const float4*)(gp1);
    float4 cQ0 = *(const float4*)(gi0);
    float4 cQ1 = *(const float4*)(gi1);

    for (int tb = 0; tb < 124; tb += 4) {
        const float4 nP0 = *(const float4*)(gp0 + tb + 4);
        const float4 nP1 = *(const float4*)(gp1 + tb + 4);
        const float4 nQ0 = *(const float4*)(gi0 + tb + 4);
        const float4 nQ1 = *(const float4*)(gi1 + tb + 4);
        step(cP0.x, cP1.x, cQ0.x, cQ1.x, tg[tb + 1]);
        step(cP0.y, cP1.y, cQ0.y, cQ1.y, tg[tb + 2]);
        step(cP0.z, cP1.z, cQ0.z, cQ1.z, tg[tb + 3]);
        step(cP0.w, cP1.w, cQ0.w, cQ1.w, tg[tb + 4]);
        cP0 = nP0; cP1 = nP1; cQ0 = nQ0; cQ1 = nQ1;
    }
    // t = 124, 125, 126
    step(cP0.x, cP1.x, cQ0.x, cQ1.x, tg[125]);
    step(cP0.y, cP1.y, cQ0.y, cQ1.y, tg[126]);
    step(cP0.z, cP1.z, cQ0.z, cQ1.z, tg[127]);

    if (lane == 63) out[b] = row1v;
}

// ---------------- Fallback (round-1 kernel) if ws too small ----------------
__global__ __launch_bounds__(64) void eploss_fallback(
    const float* __restrict__ pred,
    const float* __restrict__ R,
    const float* __restrict__ I,
    const int*   __restrict__ target,
    float*       __restrict__ out)
{
    const int b    = blockIdx.x;
    const int lane = threadIdx.x;
    const int j0   = 2 * lane;
    const int j1   = 2 * lane + 1;

    __shared__ int tg[NT];
    tg[j0] = target[(size_t)b * NT + j0];
    tg[j1] = target[(size_t)b * NT + j1];
    __syncthreads();

    const float* Rb = R + (size_t)b * NY * 3;
    const float R0j0 = Rb[j0 * 3 + 0];
    const float R1j0 = Rb[j0 * 3 + 1];
    const float R2j0 = Rb[j0 * 3 + 2];
    const float R0j1 = Rb[j1 * 3 + 0];
    const float R1j1 = Rb[j1 * 3 + 1];
    const float R2j1 = Rb[j1 * 3 + 2];
    const float R2m1 = __shfl_up(R2j1, 1);

    const int tgt0 = tg[0];
    const float e0 = (lane == 0) ? 1.0f : ((tgt0 == EOS) ? 1.0f : R2j0);
    const float e1 = (tgt0 == EOS) ? 1.0f : R2j1;
    float P = e0 * e1;
    #pragma unroll
    for (int s = 1; s < 64; s <<= 1) {
        float Pp = __shfl_up(P, s);
        if (lane >= s) P *= Pp;
    }
    float Pm1 = __shfl_up(P, 1);
    if (lane == 0) Pm1 = 1.0f;
    float row0v = Pm1 * e0;
    float row1v = P;

    const size_t baseP = (size_t)b * NY * C_DIM;
    const float* pr0 = pred + baseP + (size_t)j0 * C_DIM;
    const float* pr1 = pred + baseP + (size_t)j1 * C_DIM;
    const float* Ii0 = I    + baseP + (size_t)j0 * C_DIM;
    const float* Ii1 = I    + baseP + (size_t)j1 * C_DIM;

    int tgt = tg[0];
    float p0 = pr0[tgt], p1 = pr1[tgt];
    float q0 = Ii0[tgt], q1 = Ii1[tgt];

    for (int t = 0; t < NT - 1; ++t) {
        const int tgt_next = tg[t + 1];
        float np0 = 0.f, np1 = 0.f, nq0 = 0.f, nq1 = 0.f;
        if (t + 1 < NT - 1) {
            np0 = pr0[tgt_next]; np1 = pr1[tgt_next];
            nq0 = Ii0[tgt_next]; nq1 = Ii1[tgt_next];
        }
        const float pC0 = R0j0 * p0;
        const float pC1 = R0j1 * p1;
        const float pI0 = R1j0 * q0;
        const float pI1 = (lane == 63) ? q1 : R1j1 * q1;
        const float m1 = row1v * pC1;
        const float mprev = __shfl_up(m1, 1);
        const float a0 = row0v * pI0 + ((lane == 0) ? 0.0f : mprev);
        const float a1 = row0v * pC0 + row1v * pI1;
        const bool eosn = (tgt_next == EOS);
        const float d0 = (lane == 0 || eosn) ? 1.0f : R2m1;
        const float d1 = eosn ? 1.0f : R2j0;
        float A = a1 + d1 * a0;
        float D = d1 * d0;
        #pragma unroll
        for (int s = 1; s < 64; s <<= 1) {
            float Ap = __shfl_up(A, s);
            float Dp = __shfl_up(D, s);
            if (lane >= s) { A = A + Ap * D; D = D * Dp; }
        }
        const float Xm1 = __shfl_up(A, 1);
        row0v = a0 + ((lane == 0) ? 0.0f : d0 * Xm1);
        row1v = A;
        p0 = np0; p1 = np1; q0 = nq0; q1 = nq1;
    }

    if (lane == 63) out[b] = row1v;
}

extern "C" void kernel_launch(void* const* d_in, const int* in_sizes, int n_in,
                              void* d_out, int out_size, void* d_ws, size_t ws_size,
                              hipStream_t stream) {
    const float* pred   = (const float*)d_in[0];
    const float* R      = (const float*)d_in[1];
    const float* I      = (const float*)d_in[2];
    const int*   target = (const int*)d_in[3];
    float* out = (float*)d_out;

    const size_t need = 2ull * B_DIM * NY * NT * sizeof(float);  // 134 MB
    if (ws_size >= need) {
        float* Gp = (float*)d_ws;
        float* Gi = Gp + (size_t)B_DIM * NY * NT;
        gather_direct<<<dim3(B_DIM * NY / 4), dim3(256), 0, stream>>>(pred, I, target, Gp, Gi);
        scan_kernel<<<dim3(B_DIM), dim3(64), 0, stream>>>(R, target, Gp, Gi, out);
    } else {
        eploss_fallback<<<dim3(B_DIM), dim3(64), 0, stream>>>(pred, R, I, target, out);
    }
}